// Round 1
// baseline (815.051 us; speedup 1.0000x reference)
//
#include <hip/hip_runtime.h>
#include <stdint.h>

typedef unsigned short u16;
typedef unsigned int u32;
typedef __attribute__((ext_vector_type(4))) u16 u16x4;
typedef __attribute__((ext_vector_type(8))) u16 u16x8;
typedef __attribute__((ext_vector_type(8))) short bf16x8;
typedef __attribute__((ext_vector_type(4))) float f32x4;

#define DEVFN __device__ __forceinline__

DEVFN u16 f2bf(float f) {
  union { float f; u32 u; } x; x.f = f;
  u32 u = x.u;
  return (u16)((u + 0x7fffu + ((u >> 16) & 1u)) >> 16);
}

// ---------------- fp32 -> bf16 convert ----------------
__global__ void cvt_kernel(const float* __restrict__ in, u16* __restrict__ out, int n4) {
  const int stride = gridDim.x * blockDim.x;
  for (int i = blockIdx.x * blockDim.x + threadIdx.x; i < n4; i += stride) {
    float4 v = reinterpret_cast<const float4*>(in)[i];
    u16x4 o;
    o.x = f2bf(v.x); o.y = f2bf(v.y); o.z = f2bf(v.z); o.w = f2bf(v.w);
    reinterpret_cast<u16x4*>(out)[i] = o;
  }
}

// ---------------- bf16 GEMM: C = A @ Bt^T + bias ----------------
// A: [M][K] bf16 row-major, Bt: [N][K] bf16 row-major (i.e. B transposed)
// MODE 0: out bf16 (u16), MODE 1: out fp32
// tile 128x128, BK=64, 4 waves (2x2), each wave 64x64 = 4x4 frags of 16x16x32
template <int MODE>
__global__ __launch_bounds__(256) void gemm_kernel(
    const u16* __restrict__ A, const u16* __restrict__ Bt,
    const float* __restrict__ bias, void* __restrict__ Out,
    int K, int ldo) {
  __shared__ u16 sA[128 * 64];
  __shared__ u16 sB[128 * 64];
  const int tid = threadIdx.x;
  const int lane = tid & 63;
  const int wid = tid >> 6;
  const int m0 = blockIdx.x * 128;
  const int n0 = blockIdx.y * 128;
  const int wr = wid >> 1, wc = wid & 1;
  const int l15 = lane & 15, lg = lane >> 4;

  f32x4 acc[4][4] = {};

  const int sr = lane >> 3;  // row within 8-row stage group
  const int ss = lane & 7;   // 16B slot within 128B row

  for (int kk = 0; kk < K; kk += 64) {
    __syncthreads();
#pragma unroll
    for (int i = 0; i < 4; ++i) {
      const int r = wid * 32 + i * 8 + sr;
      const int srcs = ss ^ (r & 7);  // pre-swizzled source -> linear LDS dest
      const u16* ga = A + (size_t)(m0 + r) * K + kk + srcs * 8;
      const u16* gb = Bt + (size_t)(n0 + r) * K + kk + srcs * 8;
      __builtin_amdgcn_global_load_lds(
          (const __attribute__((address_space(1))) void*)ga,
          (__attribute__((address_space(3))) void*)(sA + (wid * 32 + i * 8) * 64), 16, 0, 0);
      __builtin_amdgcn_global_load_lds(
          (const __attribute__((address_space(1))) void*)gb,
          (__attribute__((address_space(3))) void*)(sB + (wid * 32 + i * 8) * 64), 16, 0, 0);
    }
    __syncthreads();
#pragma unroll
    for (int ks = 0; ks < 2; ++ks) {
      bf16x8 af[4], bfr[4];
#pragma unroll
      for (int mi = 0; mi < 4; ++mi) {
        const int m = wr * 64 + mi * 16 + l15;
        const int slot = (ks * 4 + lg) ^ (m & 7);
        af[mi] = *reinterpret_cast<const bf16x8*>(sA + m * 64 + slot * 8);
      }
#pragma unroll
      for (int ni = 0; ni < 4; ++ni) {
        const int n = wc * 64 + ni * 16 + l15;
        const int slot = (ks * 4 + lg) ^ (n & 7);
        bfr[ni] = *reinterpret_cast<const bf16x8*>(sB + n * 64 + slot * 8);
      }
#pragma unroll
      for (int mi = 0; mi < 4; ++mi)
#pragma unroll
        for (int ni = 0; ni < 4; ++ni)
          acc[mi][ni] = __builtin_amdgcn_mfma_f32_16x16x32_bf16(af[mi], bfr[ni], acc[mi][ni], 0, 0, 0);
    }
  }

#pragma unroll
  for (int mi = 0; mi < 4; ++mi) {
#pragma unroll
    for (int ni = 0; ni < 4; ++ni) {
      const int col = n0 + wc * 64 + ni * 16 + l15;
      const float bv = bias[col];
      const int rbase = m0 + wr * 64 + mi * 16 + lg * 4;
#pragma unroll
      for (int r = 0; r < 4; ++r) {
        const float v = acc[mi][ni][r] + bv;
        if (MODE == 0) {
          ((u16*)Out)[(size_t)(rbase + r) * ldo + col] = f2bf(v);
        } else {
          ((float*)Out)[(size_t)(rbase + r) * ldo + col] = v;
        }
      }
    }
  }
}

// ---------------- attention: one wave per (window, head) ----------------
// qkv: [2048*49][1536] bf16 (q|k|v each 512 = 16 heads * 32)
// attn_out: [2048*49][512] bf16
__global__ __launch_bounds__(64) void attn_kernel(
    const u16* __restrict__ qkv, const float* __restrict__ bias_table,
    const int* __restrict__ rel_index, const float* __restrict__ mask,
    u16* __restrict__ attn_out) {
  const int b = blockIdx.x >> 4;
  const int h = blockIdx.x & 15;
  const int lane = threadIdx.x;
  const int l15 = lane & 15, lg = lane >> 4;

  __shared__ u16 sQK[2][64][40];  // q,k rows padded to 80B
  __shared__ u16 sVT[32][72];     // v transposed [d][j], 144B rows

  // zero-init (padding rows/cols must be 0)
  for (int i = lane; i < 2560; i += 64) ((u32*)sQK)[i] = 0;
  for (int i = lane; i < 1152; i += 64) ((u32*)sVT)[i] = 0;
  __syncthreads();

  // load q, k, v (49 tokens x 32 dims, 16B chunks)
  const size_t rowbase = (size_t)b * 49 * 1536 + h * 32;
  for (int c = lane; c < 196; c += 64) {
    const int n = c >> 2, dg = c & 3;
    const size_t src = rowbase + (size_t)n * 1536 + dg * 8;
    u16x8 qv = *reinterpret_cast<const u16x8*>(qkv + src);
    u16x8 kv = *reinterpret_cast<const u16x8*>(qkv + src + 512);
    u16x8 vv = *reinterpret_cast<const u16x8*>(qkv + src + 1024);
    *reinterpret_cast<u16x8*>(&sQK[0][n][dg * 8]) = qv;
    *reinterpret_cast<u16x8*>(&sQK[1][n][dg * 8]) = kv;
#pragma unroll
    for (int j = 0; j < 8; ++j) sVT[dg * 8 + j][n] = vv[j];
  }
  __syncthreads();

  // S = Q @ K^T  (64x64 padded, K=32 in one MFMA step)
  f32x4 s[4][4] = {};
  {
    bf16x8 aq[4], bk[4];
#pragma unroll
    for (int mi = 0; mi < 4; ++mi)
      aq[mi] = *reinterpret_cast<const bf16x8*>(&sQK[0][mi * 16 + l15][lg * 8]);
#pragma unroll
    for (int ni = 0; ni < 4; ++ni)
      bk[ni] = *reinterpret_cast<const bf16x8*>(&sQK[1][ni * 16 + l15][lg * 8]);
#pragma unroll
    for (int mi = 0; mi < 4; ++mi)
#pragma unroll
      for (int ni = 0; ni < 4; ++ni)
        s[mi][ni] = __builtin_amdgcn_mfma_f32_16x16x32_bf16(aq[mi], bk[ni], s[mi][ni], 0, 0, 0);
  }

  // scale + rel-pos bias + mask; pad -> -1e30
  const float scale = 0.17677669529663687f;
  const float* maskw = mask + (size_t)(b & 63) * 2401;
#pragma unroll
  for (int mi = 0; mi < 4; ++mi) {
#pragma unroll
    for (int ni = 0; ni < 4; ++ni) {
      const int j = ni * 16 + l15;
#pragma unroll
      for (int r = 0; r < 4; ++r) {
        const int i = mi * 16 + lg * 4 + r;
        float v;
        if (j < 49 && i < 49) {
          const int ri = rel_index[i * 49 + j];
          v = s[mi][ni][r] * scale + bias_table[ri * 16 + h] + maskw[i * 49 + j];
        } else {
          v = -1e30f;
        }
        s[mi][ni][r] = v;
      }
    }
  }

  // row softmax (row i = mi*16 + lg*4 + r, cols across ni and lane&15)
  float rsum[4][4];
#pragma unroll
  for (int mi = 0; mi < 4; ++mi) {
#pragma unroll
    for (int r = 0; r < 4; ++r) {
      float m_ = fmaxf(fmaxf(s[mi][0][r], s[mi][1][r]), fmaxf(s[mi][2][r], s[mi][3][r]));
      m_ = fmaxf(m_, __shfl_xor(m_, 1));
      m_ = fmaxf(m_, __shfl_xor(m_, 2));
      m_ = fmaxf(m_, __shfl_xor(m_, 4));
      m_ = fmaxf(m_, __shfl_xor(m_, 8));
      float sum = 0.f;
#pragma unroll
      for (int ni = 0; ni < 4; ++ni) {
        const float e = __expf(s[mi][ni][r] - m_);
        s[mi][ni][r] = e;
        sum += e;
      }
      sum += __shfl_xor(sum, 1);
      sum += __shfl_xor(sum, 2);
      sum += __shfl_xor(sum, 4);
      sum += __shfl_xor(sum, 8);
      rsum[mi][r] = sum;
    }
  }

  __syncthreads();  // all QK^T LDS reads done before P overwrites q/k space
  u16* sP = (u16*)&sQK[0][0][0];  // [64][72] rows (144B), aliases q/k
#pragma unroll
  for (int mi = 0; mi < 4; ++mi) {
#pragma unroll
    for (int ni = 0; ni < 4; ++ni) {
      const int j = ni * 16 + l15;
#pragma unroll
      for (int r = 0; r < 4; ++r)
        sP[(mi * 16 + lg * 4 + r) * 72 + j] = f2bf(s[mi][ni][r]);
    }
  }
  __syncthreads();

  // O = P @ V  (K=64 in two MFMA steps), normalize by rsum at the end
  f32x4 o[4][2] = {};
#pragma unroll
  for (int ks = 0; ks < 2; ++ks) {
    bf16x8 ap[4], bv[2];
#pragma unroll
    for (int mi = 0; mi < 4; ++mi)
      ap[mi] = *reinterpret_cast<const bf16x8*>(sP + (mi * 16 + l15) * 72 + ks * 32 + lg * 8);
#pragma unroll
    for (int ni = 0; ni < 2; ++ni)
      bv[ni] = *reinterpret_cast<const bf16x8*>(&sVT[ni * 16 + l15][ks * 32 + lg * 8]);
#pragma unroll
    for (int mi = 0; mi < 4; ++mi)
#pragma unroll
      for (int ni = 0; ni < 2; ++ni)
        o[mi][ni] = __builtin_amdgcn_mfma_f32_16x16x32_bf16(ap[mi], bv[ni], o[mi][ni], 0, 0, 0);
  }

  const size_t obase = (size_t)b * 49 * 512 + h * 32;
#pragma unroll
  for (int mi = 0; mi < 4; ++mi) {
#pragma unroll
    for (int ni = 0; ni < 2; ++ni) {
      const int d = ni * 16 + l15;
#pragma unroll
      for (int r = 0; r < 4; ++r) {
        const int i = mi * 16 + lg * 4 + r;
        if (i < 49)
          attn_out[obase + (size_t)i * 512 + d] = f2bf(o[mi][ni][r] / rsum[mi][r]);
      }
    }
  }
}

extern "C" void kernel_launch(void* const* d_in, const int* in_sizes, int n_in,
                              void* d_out, int out_size, void* d_ws, size_t ws_size,
                              hipStream_t stream) {
  (void)in_sizes; (void)n_in; (void)out_size; (void)ws_size;
  const float* x          = (const float*)d_in[0];
  const float* w_qkv      = (const float*)d_in[1];
  const float* b_qkv      = (const float*)d_in[2];
  const float* w_proj     = (const float*)d_in[3];
  const float* b_proj     = (const float*)d_in[4];
  const float* bias_table = (const float*)d_in[5];
  const int*   rel_index  = (const int*)d_in[6];
  const float* mask       = (const float*)d_in[7];

  u16* ws     = (u16*)d_ws;
  u16* xbf    = ws;                    // 51,380,224 elems (reused as attn_out)
  u16* qkv    = ws + 51380224;         // 154,140,672 elems
  u16* wqkvb  = qkv + 154140672;       // 786,432 elems
  u16* wprojb = wqkvb + 786432;        // 262,144 elems

  cvt_kernel<<<2048, 256, 0, stream>>>(x, xbf, 51380224 / 4);
  cvt_kernel<<<192, 256, 0, stream>>>(w_qkv, wqkvb, 786432 / 4);
  cvt_kernel<<<64, 256, 0, stream>>>(w_proj, wprojb, 262144 / 4);

  gemm_kernel<0><<<dim3(784, 12), 256, 0, stream>>>(xbf, wqkvb, b_qkv, qkv, 512, 1536);
  attn_kernel<<<32768, 64, 0, stream>>>(qkv, bias_table, rel_index, mask, xbf);
  gemm_kernel<1><<<dim3(784, 4), 256, 0, stream>>>(xbf, wprojb, b_proj, d_out, 512, 512);
}

// Round 2
// 682.545 us; speedup vs baseline: 1.1941x; 1.1941x over previous
//
#include <hip/hip_runtime.h>
#include <stdint.h>

typedef unsigned short u16;
typedef unsigned int u32;
typedef __attribute__((ext_vector_type(4))) u16 u16x4;
typedef __attribute__((ext_vector_type(8))) u16 u16x8;
typedef __attribute__((ext_vector_type(8))) short bf16x8;
typedef __attribute__((ext_vector_type(4))) float f32x4;

#define DEVFN __device__ __forceinline__

DEVFN u16 f2bf(float f) {
  union { float f; u32 u; } x; x.f = f;
  u32 u = x.u;
  return (u16)((u + 0x7fffu + ((u >> 16) & 1u)) >> 16);
}

// ---------------- fp32 -> bf16 convert ----------------
__global__ void cvt_kernel(const float* __restrict__ in, u16* __restrict__ out, int n4) {
  const int stride = gridDim.x * blockDim.x;
  for (int i = blockIdx.x * blockDim.x + threadIdx.x; i < n4; i += stride) {
    float4 v = reinterpret_cast<const float4*>(in)[i];
    u16x4 o;
    o.x = f2bf(v.x); o.y = f2bf(v.y); o.z = f2bf(v.z); o.w = f2bf(v.w);
    reinterpret_cast<u16x4*>(out)[i] = o;
  }
}

// ---------------- pb[h][e] = bias_table[rel_index[e]*16 + h] ----------------
__global__ void pb_kernel(const float* __restrict__ bt, const int* __restrict__ ri,
                          float* __restrict__ pb) {
  const int h = blockIdx.x;
  const int e = blockIdx.y * 256 + threadIdx.x;
  if (e < 2401) pb[h * 2401 + e] = bt[ri[e] * 16 + h];
}

// ---------------- bf16 GEMM: C = A @ Bt^T + bias ----------------
// A: [M][K] bf16 row-major, Bt: [N][K] bf16 row-major (i.e. B transposed)
// MODE 0: out bf16 (u16), MODE 1: out fp32
// tile 128x128, BK=64, 4 waves (2x2), each wave 64x64 = 4x4 frags of 16x16x32
template <int MODE>
__global__ __launch_bounds__(256) void gemm_kernel(
    const u16* __restrict__ A, const u16* __restrict__ Bt,
    const float* __restrict__ bias, void* __restrict__ Out,
    int K, int ldo) {
  __shared__ u16 sA[128 * 64];
  __shared__ u16 sB[128 * 64];
  const int tid = threadIdx.x;
  const int lane = tid & 63;
  const int wid = tid >> 6;
  const int m0 = blockIdx.x * 128;
  const int n0 = blockIdx.y * 128;
  const int wr = wid >> 1, wc = wid & 1;
  const int l15 = lane & 15, lg = lane >> 4;

  f32x4 acc[4][4] = {};

  const int sr = lane >> 3;  // row within 8-row stage group
  const int ss = lane & 7;   // 16B slot within 128B row

  for (int kk = 0; kk < K; kk += 64) {
    __syncthreads();
#pragma unroll
    for (int i = 0; i < 4; ++i) {
      const int r = wid * 32 + i * 8 + sr;
      const int srcs = ss ^ (r & 7);  // pre-swizzled source -> linear LDS dest
      const u16* ga = A + (size_t)(m0 + r) * K + kk + srcs * 8;
      const u16* gb = Bt + (size_t)(n0 + r) * K + kk + srcs * 8;
      __builtin_amdgcn_global_load_lds(
          (const __attribute__((address_space(1))) void*)ga,
          (__attribute__((address_space(3))) void*)(sA + (wid * 32 + i * 8) * 64), 16, 0, 0);
      __builtin_amdgcn_global_load_lds(
          (const __attribute__((address_space(1))) void*)gb,
          (__attribute__((address_space(3))) void*)(sB + (wid * 32 + i * 8) * 64), 16, 0, 0);
    }
    __syncthreads();
#pragma unroll
    for (int ks = 0; ks < 2; ++ks) {
      bf16x8 af[4], bfr[4];
#pragma unroll
      for (int mi = 0; mi < 4; ++mi) {
        const int m = wr * 64 + mi * 16 + l15;
        const int slot = (ks * 4 + lg) ^ (m & 7);
        af[mi] = *reinterpret_cast<const bf16x8*>(sA + m * 64 + slot * 8);
      }
#pragma unroll
      for (int ni = 0; ni < 4; ++ni) {
        const int n = wc * 64 + ni * 16 + l15;
        const int slot = (ks * 4 + lg) ^ (n & 7);
        bfr[ni] = *reinterpret_cast<const bf16x8*>(sB + n * 64 + slot * 8);
      }
#pragma unroll
      for (int mi = 0; mi < 4; ++mi)
#pragma unroll
        for (int ni = 0; ni < 4; ++ni)
          acc[mi][ni] = __builtin_amdgcn_mfma_f32_16x16x32_bf16(af[mi], bfr[ni], acc[mi][ni], 0, 0, 0);
    }
  }

#pragma unroll
  for (int mi = 0; mi < 4; ++mi) {
#pragma unroll
    for (int ni = 0; ni < 4; ++ni) {
      const int col = n0 + wc * 64 + ni * 16 + l15;
      const float bv = bias[col];
      const int rbase = m0 + wr * 64 + mi * 16 + lg * 4;
#pragma unroll
      for (int r = 0; r < 4; ++r) {
        const float v = acc[mi][ni][r] + bv;
        if (MODE == 0) {
          ((u16*)Out)[(size_t)(rbase + r) * ldo + col] = f2bf(v);
        } else {
          ((float*)Out)[(size_t)(rbase + r) * ldo + col] = v;
        }
      }
    }
  }
}

// ---------------- attention: one wave per (window, head) ----------------
// qkv: [2048*49][1536] bf16 (q|k|v each 512 = 16 heads * 32)
// pb: [16][2401] fp32 precomputed rel-pos bias
// attn_out: [2048*49][512] bf16
__global__ __launch_bounds__(64) void attn_kernel(
    const u16* __restrict__ qkv, const float* __restrict__ pb,
    const float* __restrict__ mask, u16* __restrict__ attn_out) {
  const int b = blockIdx.x >> 4;
  const int h = blockIdx.x & 15;
  const int lane = threadIdx.x;
  const int l15 = lane & 15, lg = lane >> 4;

  __shared__ u16 sVT[32][66];  // V transposed [dim][token], 132B rows (scatter 2-way free)
  __shared__ u16 sP[64][68];   // P [row][col], 136B rows (write rows on disjoint bank groups)

  const size_t rowbase = (size_t)b * (49 * 1536) + h * 32;

  // Q,K fragments straight from global (rows >=49 clamped; masked later)
  bf16x8 aq[4], bk[4];
#pragma unroll
  for (int mi = 0; mi < 4; ++mi) {
    const int i = mi * 16 + l15;
    const int r = i < 49 ? i : 48;
    const size_t ro = rowbase + (size_t)r * 1536 + lg * 8;
    aq[mi] = *reinterpret_cast<const bf16x8*>(qkv + ro);
    bk[mi] = *reinterpret_cast<const bf16x8*>(qkv + ro + 512);
  }

  // zero sVT (cols >=49 must be deterministic-finite), then V transpose-scatter
  for (int i = lane; i < 1056; i += 64) ((u32*)sVT)[i] = 0;
  __syncthreads();
  for (int c = lane; c < 196; c += 64) {
    const int n = c >> 2, dg = c & 3;
    u16x8 vv = *reinterpret_cast<const u16x8*>(qkv + rowbase + (size_t)n * 1536 + 1024 + dg * 8);
#pragma unroll
    for (int j = 0; j < 8; ++j) sVT[dg * 8 + j][n] = vv[j];
  }

  // S = Q @ K^T  (64x64 padded, K=32 in one MFMA step)
  f32x4 s[4][4] = {};
#pragma unroll
  for (int mi = 0; mi < 4; ++mi)
#pragma unroll
    for (int ni = 0; ni < 4; ++ni)
      s[mi][ni] = __builtin_amdgcn_mfma_f32_16x16x32_bf16(aq[mi], bk[ni], s[mi][ni], 0, 0, 0);

  // scale + precomputed bias + mask (affine coalesced L2 loads); pad -> -1e30
  const float scale = 0.17677669529663687f;
  const float* pbh = pb + h * 2401;
  const float* maskw = mask + (size_t)(b & 63) * 2401;
#pragma unroll
  for (int mi = 0; mi < 4; ++mi) {
#pragma unroll
    for (int ni = 0; ni < 4; ++ni) {
      const int j = ni * 16 + l15;
#pragma unroll
      for (int r = 0; r < 4; ++r) {
        const int i = mi * 16 + lg * 4 + r;
        float v = -1e30f;
        if (j < 49 && i < 49) {
          const int e = i * 49 + j;
          v = s[mi][ni][r] * scale + pbh[e] + maskw[e];
        }
        s[mi][ni][r] = v;
      }
    }
  }

  // row softmax (row i = mi*16 + lg*4 + r, cols across ni and lane&15)
  float rsum[4][4];
#pragma unroll
  for (int mi = 0; mi < 4; ++mi) {
#pragma unroll
    for (int r = 0; r < 4; ++r) {
      float m_ = fmaxf(fmaxf(s[mi][0][r], s[mi][1][r]), fmaxf(s[mi][2][r], s[mi][3][r]));
      m_ = fmaxf(m_, __shfl_xor(m_, 1));
      m_ = fmaxf(m_, __shfl_xor(m_, 2));
      m_ = fmaxf(m_, __shfl_xor(m_, 4));
      m_ = fmaxf(m_, __shfl_xor(m_, 8));
      float sum = 0.f;
#pragma unroll
      for (int ni = 0; ni < 4; ++ni) {
        const float e = __expf(s[mi][ni][r] - m_);
        s[mi][ni][r] = e;
        sum += e;
      }
      sum += __shfl_xor(sum, 1);
      sum += __shfl_xor(sum, 2);
      sum += __shfl_xor(sum, 4);
      sum += __shfl_xor(sum, 8);
      rsum[mi][r] = sum;
    }
  }

  __syncthreads();  // sVT scatter visible before PV; nothing reads sP yet
#pragma unroll
  for (int mi = 0; mi < 4; ++mi) {
#pragma unroll
    for (int ni = 0; ni < 4; ++ni) {
      const int j = ni * 16 + l15;
#pragma unroll
      for (int r = 0; r < 4; ++r)
        sP[mi * 16 + lg * 4 + r][j] = f2bf(s[mi][ni][r]);
    }
  }
  __syncthreads();

  // O = P @ V  (K=64 in two MFMA steps), normalize by rsum at the end
  f32x4 o[4][2] = {};
#pragma unroll
  for (int ks = 0; ks < 2; ++ks) {
    bf16x8 ap[4], bv[2];
#pragma unroll
    for (int mi = 0; mi < 4; ++mi)
      ap[mi] = *reinterpret_cast<const bf16x8*>(&sP[mi * 16 + l15][ks * 32 + lg * 8]);
#pragma unroll
    for (int ni = 0; ni < 2; ++ni)
      bv[ni] = *reinterpret_cast<const bf16x8*>(&sVT[ni * 16 + l15][ks * 32 + lg * 8]);
#pragma unroll
    for (int mi = 0; mi < 4; ++mi)
#pragma unroll
      for (int ni = 0; ni < 2; ++ni)
        o[mi][ni] = __builtin_amdgcn_mfma_f32_16x16x32_bf16(ap[mi], bv[ni], o[mi][ni], 0, 0, 0);
  }

  const size_t obase = (size_t)b * 49 * 512 + h * 32;
#pragma unroll
  for (int mi = 0; mi < 4; ++mi) {
#pragma unroll
    for (int ni = 0; ni < 2; ++ni) {
      const int d = ni * 16 + l15;
#pragma unroll
      for (int r = 0; r < 4; ++r) {
        const int i = mi * 16 + lg * 4 + r;
        if (i < 49)
          attn_out[obase + (size_t)i * 512 + d] = f2bf(o[mi][ni][r] / rsum[mi][r]);
      }
    }
  }
}

extern "C" void kernel_launch(void* const* d_in, const int* in_sizes, int n_in,
                              void* d_out, int out_size, void* d_ws, size_t ws_size,
                              hipStream_t stream) {
  (void)in_sizes; (void)n_in; (void)out_size; (void)ws_size;
  const float* x          = (const float*)d_in[0];
  const float* w_qkv      = (const float*)d_in[1];
  const float* b_qkv      = (const float*)d_in[2];
  const float* w_proj     = (const float*)d_in[3];
  const float* b_proj     = (const float*)d_in[4];
  const float* bias_table = (const float*)d_in[5];
  const int*   rel_index  = (const int*)d_in[6];
  const float* mask       = (const float*)d_in[7];

  u16* ws     = (u16*)d_ws;
  u16* xbf    = ws;                    // 51,380,224 elems (reused as attn_out)
  u16* qkv    = ws + 51380224;         // 154,140,672 elems
  u16* wqkvb  = qkv + 154140672;       // 786,432 elems
  u16* wprojb = wqkvb + 786432;        // 262,144 elems
  float* pb   = (float*)(wprojb + 262144);  // 16*2401 floats (154 KB)

  cvt_kernel<<<2048, 256, 0, stream>>>(x, xbf, 51380224 / 4);
  cvt_kernel<<<192, 256, 0, stream>>>(w_qkv, wqkvb, 786432 / 4);
  cvt_kernel<<<64, 256, 0, stream>>>(w_proj, wprojb, 262144 / 4);
  pb_kernel<<<dim3(16, 10), 256, 0, stream>>>(bias_table, rel_index, pb);

  gemm_kernel<0><<<dim3(784, 12), 256, 0, stream>>>(xbf, wqkvb, b_qkv, qkv, 512, 1536);
  attn_kernel<<<32768, 64, 0, stream>>>(qkv, pb, mask, xbf);
  gemm_kernel<1><<<dim3(784, 4), 256, 0, stream>>>(xbf, wprojb, b_proj, d_out, 512, 512);
}

// Round 3
// 641.200 us; speedup vs baseline: 1.2711x; 1.0645x over previous
//
#include <hip/hip_runtime.h>
#include <stdint.h>

typedef unsigned short u16;
typedef unsigned int u32;
typedef __attribute__((ext_vector_type(4))) u16 u16x4;
typedef __attribute__((ext_vector_type(8))) u16 u16x8;
typedef __attribute__((ext_vector_type(2))) u32 u32x2;
typedef __attribute__((ext_vector_type(8))) short bf16x8;
typedef __attribute__((ext_vector_type(4))) float f32x4;

#define DEVFN __device__ __forceinline__

DEVFN u16 f2bf(float f) {
  union { float f; u32 u; } x; x.f = f;
  u32 u = x.u;
  return (u16)((u + 0x7fffu + ((u >> 16) & 1u)) >> 16);
}

// ---------------- fp32 -> bf16 convert ----------------
__global__ void cvt_kernel(const float* __restrict__ in, u16* __restrict__ out, int n4) {
  const int stride = gridDim.x * blockDim.x;
  for (int i = blockIdx.x * blockDim.x + threadIdx.x; i < n4; i += stride) {
    float4 v = reinterpret_cast<const float4*>(in)[i];
    u16x4 o;
    o.x = f2bf(v.x); o.y = f2bf(v.y); o.z = f2bf(v.z); o.w = f2bf(v.w);
    reinterpret_cast<u16x4*>(out)[i] = o;
  }
}

// ---------------- padded bias table: pbp[h][i][j64] (pad = 0) ----------------
__global__ void pbp_kernel(const float* __restrict__ bt, const int* __restrict__ ri,
                           float* __restrict__ pbp) {
  const int h = blockIdx.x;
  for (int t = threadIdx.x; t < 4096; t += 256) {
    const int i = t >> 6, j = t & 63;
    float v = 0.f;
    if (i < 49 && j < 49) v = bt[ri[i * 49 + j] * 16 + h];
    pbp[h * 4096 + t] = v;
  }
}

// ---------------- padded mask: maskp[w][i][j64] (pad = -1e30) ----------------
__global__ void maskp_kernel(const float* __restrict__ mask, float* __restrict__ maskp) {
  const int w = blockIdx.x;
  for (int t = threadIdx.x; t < 4096; t += 256) {
    const int i = t >> 6, j = t & 63;
    float v = -1e30f;
    if (i < 49 && j < 49) v = mask[w * 2401 + i * 49 + j];
    maskp[w * 4096 + t] = v;
  }
}

// ---------------- bf16 GEMM: C = A @ Bt^T + bias ----------------
// A: [M][K] bf16 row-major, Bt: [N][K] bf16 row-major (i.e. B transposed)
// MODE 0: out bf16 (u16), MODE 1: out fp32
// tile 128x128, BK=64, 4 waves (2x2), each wave 64x64 = 4x4 frags of 16x16x32
template <int MODE>
__global__ __launch_bounds__(256) void gemm_kernel(
    const u16* __restrict__ A, const u16* __restrict__ Bt,
    const float* __restrict__ bias, void* __restrict__ Out,
    int K, int ldo) {
  __shared__ u16 sA[128 * 64];
  __shared__ u16 sB[128 * 64];
  const int tid = threadIdx.x;
  const int lane = tid & 63;
  const int wid = tid >> 6;
  const int m0 = blockIdx.x * 128;
  const int n0 = blockIdx.y * 128;
  const int wr = wid >> 1, wc = wid & 1;
  const int l15 = lane & 15, lg = lane >> 4;

  f32x4 acc[4][4] = {};

  const int sr = lane >> 3;  // row within 8-row stage group
  const int ss = lane & 7;   // 16B slot within 128B row

  for (int kk = 0; kk < K; kk += 64) {
    __syncthreads();
#pragma unroll
    for (int i = 0; i < 4; ++i) {
      const int r = wid * 32 + i * 8 + sr;
      const int srcs = ss ^ (r & 7);  // pre-swizzled source -> linear LDS dest
      const u16* ga = A + (size_t)(m0 + r) * K + kk + srcs * 8;
      const u16* gb = Bt + (size_t)(n0 + r) * K + kk + srcs * 8;
      __builtin_amdgcn_global_load_lds(
          (const __attribute__((address_space(1))) void*)ga,
          (__attribute__((address_space(3))) void*)(sA + (wid * 32 + i * 8) * 64), 16, 0, 0);
      __builtin_amdgcn_global_load_lds(
          (const __attribute__((address_space(1))) void*)gb,
          (__attribute__((address_space(3))) void*)(sB + (wid * 32 + i * 8) * 64), 16, 0, 0);
    }
    __syncthreads();
#pragma unroll
    for (int ks = 0; ks < 2; ++ks) {
      bf16x8 af[4], bfr[4];
#pragma unroll
      for (int mi = 0; mi < 4; ++mi) {
        const int m = wr * 64 + mi * 16 + l15;
        const int slot = (ks * 4 + lg) ^ (m & 7);
        af[mi] = *reinterpret_cast<const bf16x8*>(sA + m * 64 + slot * 8);
      }
#pragma unroll
      for (int ni = 0; ni < 4; ++ni) {
        const int n = wc * 64 + ni * 16 + l15;
        const int slot = (ks * 4 + lg) ^ (n & 7);
        bfr[ni] = *reinterpret_cast<const bf16x8*>(sB + n * 64 + slot * 8);
      }
#pragma unroll
      for (int mi = 0; mi < 4; ++mi)
#pragma unroll
        for (int ni = 0; ni < 4; ++ni)
          acc[mi][ni] = __builtin_amdgcn_mfma_f32_16x16x32_bf16(af[mi], bfr[ni], acc[mi][ni], 0, 0, 0);
    }
  }

#pragma unroll
  for (int mi = 0; mi < 4; ++mi) {
#pragma unroll
    for (int ni = 0; ni < 4; ++ni) {
      const int col = n0 + wc * 64 + ni * 16 + l15;
      const float bv = bias[col];
      const int rbase = m0 + wr * 64 + mi * 16 + lg * 4;
#pragma unroll
      for (int r = 0; r < 4; ++r) {
        const float v = acc[mi][ni][r] + bv;
        if (MODE == 0) {
          ((u16*)Out)[(size_t)(rbase + r) * ldo + col] = f2bf(v);
        } else {
          ((float*)Out)[(size_t)(rbase + r) * ldo + col] = v;
        }
      }
    }
  }
}

// ---------------- attention: one wave per (window, head), swapped QK^T ----------------
// qkv: [2048*49][1536] bf16 (q|k|v each 512 = 16 heads * 32)
// pbp: [16][64][64] fp32 padded bias;  maskp: [64][64][64] fp32 padded mask (-1e30 pad)
// attn_out: [2048*49][512] bf16
__global__ __launch_bounds__(64) void attn_kernel(
    const u16* __restrict__ qkv, const float* __restrict__ pbp,
    const float* __restrict__ maskp, u16* __restrict__ attn_out) {
  const int b = blockIdx.x >> 4;
  const int h = blockIdx.x & 15;
  const int lane = threadIdx.x;
  const int l15 = lane & 15, lg = lane >> 4;

  __shared__ u16 sVT[32][72];  // V transposed [dim][token]
  __shared__ u16 sP[64][72];   // P [q][j]

  // zero sVT (padding cols must be 0: P=0 * garbage would NaN otherwise)
  for (int i = lane; i < 1152; i += 64) ((u32*)sVT)[i] = 0;

  const size_t rowbase = (size_t)b * (49 * 1536) + h * 32;

  // V loads into regs (scatter after barrier)
  u16x8 vv[4];
  int vok[4], vn[4], vd[4];
#pragma unroll
  for (int it = 0; it < 4; ++it) {
    const int c = it * 64 + lane;
    vok[it] = c < 196;
    const int cc = vok[it] ? c : 195;
    vn[it] = cc >> 2; vd[it] = cc & 3;
    vv[it] = *reinterpret_cast<const u16x8*>(qkv + rowbase + (size_t)vn[it] * 1536 + 1024 + vd[it] * 8);
  }

  // Q,K fragments straight from global (rows >=49 clamped; padding handled by maskp)
  bf16x8 aq[4], bk[4];
#pragma unroll
  for (int t = 0; t < 4; ++t) {
    const int i = t * 16 + l15;
    const int r = i < 49 ? i : 48;
    const size_t ro = rowbase + (size_t)r * 1536 + lg * 8;
    aq[t] = *reinterpret_cast<const bf16x8*>(qkv + ro);
    bk[t] = *reinterpret_cast<const bf16x8*>(qkv + ro + 512);
  }

  __syncthreads();  // sVT zeroing complete before scatter
#pragma unroll
  for (int it = 0; it < 4; ++it) {
    if (vok[it]) {
#pragma unroll
      for (int j = 0; j < 8; ++j) sVT[vd[it] * 8 + j][vn[it]] = vv[it][j];
    }
  }

  // S^T = K @ Q^T: sT[kt][qt], lane holds S[q=qt*16+l15][j=kt*16+lg*4+r]
  f32x4 sT[4][4] = {};
#pragma unroll
  for (int kt = 0; kt < 4; ++kt)
#pragma unroll
    for (int qt = 0; qt < 4; ++qt)
      sT[kt][qt] = __builtin_amdgcn_mfma_f32_16x16x32_bf16(bk[kt], aq[qt], sT[kt][qt], 0, 0, 0);

  const float scale = 0.17677669529663687f;
  const float* pbh = pbp + (h << 12);
  const float* mw = maskp + ((size_t)(b & 63) << 12);

  // per q-tile: bias+mask, lane-local softmax over j, normalize, pack -> sP
#pragma unroll
  for (int qt = 0; qt < 4; ++qt) {
    const int i = qt * 16 + l15;
    const float* pr = pbh + i * 64 + lg * 4;
    const float* mr = mw + i * 64 + lg * 4;
    float v[4][4];
    float mx = -3e38f;
#pragma unroll
    for (int kt = 0; kt < 4; ++kt) {
      f32x4 pv = *reinterpret_cast<const f32x4*>(pr + kt * 16);
      f32x4 mv = *reinterpret_cast<const f32x4*>(mr + kt * 16);
#pragma unroll
      for (int r = 0; r < 4; ++r) {
        const float val = fmaf(sT[kt][qt][r], scale, pv[r] + mv[r]);
        v[kt][r] = val;
        mx = fmaxf(mx, val);
      }
    }
    mx = fmaxf(mx, __shfl_xor(mx, 16));
    mx = fmaxf(mx, __shfl_xor(mx, 32));
    float sum = 0.f;
#pragma unroll
    for (int kt = 0; kt < 4; ++kt)
#pragma unroll
      for (int r = 0; r < 4; ++r) {
        const float e = __expf(v[kt][r] - mx);
        v[kt][r] = e;
        sum += e;
      }
    sum += __shfl_xor(sum, 16);
    sum += __shfl_xor(sum, 32);
    const float rinv = 1.0f / sum;
#pragma unroll
    for (int kt = 0; kt < 4; ++kt) {
      u32x2 wv;
      wv[0] = (u32)f2bf(v[kt][0] * rinv) | ((u32)f2bf(v[kt][1] * rinv) << 16);
      wv[1] = (u32)f2bf(v[kt][2] * rinv) | ((u32)f2bf(v[kt][3] * rinv) << 16);
      *reinterpret_cast<u32x2*>(&sP[i][kt * 16 + lg * 4]) = wv;
    }
  }
  __syncthreads();

  // O = P @ V  (K=64 in two MFMA steps); P already normalized
  f32x4 o[4][2] = {};
#pragma unroll
  for (int ks = 0; ks < 2; ++ks) {
    bf16x8 ap[4], bv[2];
#pragma unroll
    for (int mi = 0; mi < 4; ++mi)
      ap[mi] = *reinterpret_cast<const bf16x8*>(&sP[mi * 16 + l15][ks * 32 + lg * 8]);
#pragma unroll
    for (int ni = 0; ni < 2; ++ni)
      bv[ni] = *reinterpret_cast<const bf16x8*>(&sVT[ni * 16 + l15][ks * 32 + lg * 8]);
#pragma unroll
    for (int mi = 0; mi < 4; ++mi)
#pragma unroll
      for (int ni = 0; ni < 2; ++ni)
        o[mi][ni] = __builtin_amdgcn_mfma_f32_16x16x32_bf16(ap[mi], bv[ni], o[mi][ni], 0, 0, 0);
  }

  const size_t obase = (size_t)b * 49 * 512 + h * 32;
#pragma unroll
  for (int mi = 0; mi < 4; ++mi) {
#pragma unroll
    for (int r = 0; r < 4; ++r) {
      const int i = mi * 16 + lg * 4 + r;
      if (i < 49) {
#pragma unroll
        for (int ni = 0; ni < 2; ++ni)
          attn_out[obase + (size_t)i * 512 + ni * 16 + l15] = f2bf(o[mi][ni][r]);
      }
    }
  }
}

extern "C" void kernel_launch(void* const* d_in, const int* in_sizes, int n_in,
                              void* d_out, int out_size, void* d_ws, size_t ws_size,
                              hipStream_t stream) {
  (void)in_sizes; (void)n_in; (void)out_size; (void)ws_size;
  const float* x          = (const float*)d_in[0];
  const float* w_qkv      = (const float*)d_in[1];
  const float* b_qkv      = (const float*)d_in[2];
  const float* w_proj     = (const float*)d_in[3];
  const float* b_proj     = (const float*)d_in[4];
  const float* bias_table = (const float*)d_in[5];
  const int*   rel_index  = (const int*)d_in[6];
  const float* mask       = (const float*)d_in[7];

  u16* ws     = (u16*)d_ws;
  u16* xbf    = ws;                    // 51,380,224 elems (reused as attn_out)
  u16* qkv    = ws + 51380224;         // 154,140,672 elems
  u16* wqkvb  = qkv + 154140672;       // 786,432 elems
  u16* wprojb = wqkvb + 786432;        // 262,144 elems
  float* pbp  = (float*)(wprojb + 262144);  // 16*4096 floats
  float* mkp  = pbp + 16 * 4096;            // 64*4096 floats

  cvt_kernel<<<2048, 256, 0, stream>>>(x, xbf, 51380224 / 4);
  cvt_kernel<<<192, 256, 0, stream>>>(w_qkv, wqkvb, 786432 / 4);
  cvt_kernel<<<64, 256, 0, stream>>>(w_proj, wprojb, 262144 / 4);
  pbp_kernel<<<16, 256, 0, stream>>>(bias_table, rel_index, pbp);
  maskp_kernel<<<64, 256, 0, stream>>>(mask, mkp);

  gemm_kernel<0><<<dim3(784, 12), 256, 0, stream>>>(xbf, wqkvb, b_qkv, qkv, 512, 1536);
  attn_kernel<<<32768, 64, 0, stream>>>(qkv, pbp, mkp, xbf);
  gemm_kernel<1><<<dim3(784, 4), 256, 0, stream>>>(xbf, wprojb, b_proj, d_out, 512, 512);
}